// Round 8
// baseline (188.405 us; speedup 1.0000x reference)
//
#include <hip/hip_runtime.h>
#include <hip/hip_bf16.h>
#include <math.h>

#define NH 8
#define HS 64
#define VOCAB 16384
#define QPH 2048                         // queries per head = b(4) * t(512)
#define NSLICE 32                        // vocab slices (512 rows each)
// fold 1/sqrt(512) * log2(e) into Q so the epilogue is p = exp2(score)
#define QSCALE (0.04419417382415922f * 1.4426950408889634f)

typedef __attribute__((ext_vector_type(8))) short bf16x8;
typedef __attribute__((ext_vector_type(4))) float f32x4;

static __device__ __forceinline__ unsigned short f2bf(float f) {
    __hip_bfloat16 h = __float2bfloat16(f);
    unsigned short u;
    __builtin_memcpy(&u, &h, 2);
    return u;
}

static __device__ __forceinline__ float fexp2(float x) {
#if __has_builtin(__builtin_amdgcn_exp2f)
    return __builtin_amdgcn_exp2f(x);     // v_exp_f32 directly
#else
    return __expf(x * 0.6931471805599453f);
#endif
}

// ---------------- Kernel 1: fused prep -----------------------------------------------
// blocks [0,8192):   E -> bf16 cast + g[n][v] = E[n][v,:] . dec_w[n*64:]
// blocks [8192,12288): Q = LayerNorm(enc(x) + PE) * QSCALE -> bf16, wave per row
__global__ void prep(const float* __restrict__ x, const float* __restrict__ emb,
                     const float* __restrict__ enc_w, const float* __restrict__ enc_b,
                     const float* __restrict__ ln_w, const float* __restrict__ ln_b,
                     const float* __restrict__ dec_w,
                     unsigned short* __restrict__ qbf, unsigned short* __restrict__ ebf,
                     float* __restrict__ g) {
    if (blockIdx.x < 8192) {
        int i4  = blockIdx.x * 256 + threadIdx.x;   // float4 index, total 2097152
        int row = i4 >> 4;                          // (n, v) row
        int c   = i4 & 15;
        int n   = row >> 14;
        f32x4 v = ((const f32x4*)emb)[i4];
        ushort4 u = make_ushort4(f2bf(v.x), f2bf(v.y), f2bf(v.z), f2bf(v.w));
        ((ushort4*)ebf)[i4] = u;
        const float* dw = dec_w + n * 64 + c * 4;
        float p = v.x * dw[0] + v.y * dw[1] + v.z * dw[2] + v.w * dw[3];
        p += __shfl_xor(p, 1); p += __shfl_xor(p, 2);
        p += __shfl_xor(p, 4); p += __shfl_xor(p, 8);
        if (c == 0) g[row] = p;
    } else {
        int row  = (blockIdx.x - 8192) * 4 + (threadIdx.x >> 6);  // n*2048 + q
        int h    = threadIdx.x & 63;
        int n = row >> 11;
        int q = row & 2047;
        int t = q & 511;
        float xv = x[q];
        int d = n * 64 + h;
        float h2  = (float)(h & ~1);
        float div = __expf(h2 * (-9.210340371976184f / 64.0f));
        float ang = (float)t * div;
        float pe  = (h & 1) ? __cosf(ang) : __sinf(ang);
        float v = xv * enc_w[d] + enc_b[d] + pe;
        float s = v;
        #pragma unroll
        for (int off = 1; off < 64; off <<= 1) s += __shfl_xor(s, off);
        float mu = s * (1.0f / 64.0f);
        float dd = v - mu;
        float s2 = dd * dd;
        #pragma unroll
        for (int off = 1; off < 64; off <<= 1) s2 += __shfl_xor(s2, off);
        float var = s2 * (1.0f / 64.0f);
        float y = dd * rsqrtf(var + 1e-5f) * ln_w[h] + ln_b[h];
        qbf[row * 64 + h] = f2bf(y * QSCALE);
    }
}

// ---------------- Kernel 2: attn -----------------------------------------------------
// grid 2048 = qchunk(8)*256 + vslice(32)*8 + head(8); block 256 (4 waves).
// blockIdx % 8 == head: each XCD's share touches ONE head's E (2MB < 4MB L2).
// Wave w: 64 q (4 q-tiles, Q persistent 32 VGPR) x 512-row vocab slice, trip-16
// K-loop with unroll DISABLED. 8 blocks/CU -> 32 waves/CU capacity.
// CODEGEN NOTES (hard-won):
//  - __launch_bounds__(256,4) NOT (,8): the ,8 hint forced 32 VGPRs -> Q frags
//    spilled to scratch (R4: WRITE 4MB->1.5GB, 770us).
//  - K-loop must NOT fully unroll: at trip 16 + default unrolling LLVM hoists
//    all loads, blows the register budget, spills in-loop (R5: FETCH 384MB,
//    WRITE 455MB, 204us). Guarded here with clang loop unroll(disable).
//  - q/wave must stay 64: halving to 32 doubled per-wave E traffic (R6: 143us).
//  - manual 1-deep prefetch: compiler sinks it back (R7: VGPR 52 unchanged,
//    79us ~= R3) — kept since harmless, but not load-bearing.
__global__ void __launch_bounds__(256, 4)
attn(const unsigned short* __restrict__ qbf, const unsigned short* __restrict__ ebf,
     const float* __restrict__ g, float2* __restrict__ part) {
    int tid  = threadIdx.x;
    int w    = tid >> 6;
    int lane = tid & 63;
    int quad = lane >> 4;
    int l15  = lane & 15;
    int head   = blockIdx.x & 7;
    int vslice = (blockIdx.x >> 3) & 31;   // 32 slices x 512 rows
    int qchunk = blockIdx.x >> 8;          // 8 chunks x 256 q
    int qbase  = (qchunk * 4 + w) * 64;    // 64 q per wave

    // persistent Q B-frags: B[k=hs][n=q], lane: n=l15, k = kf*32 + quad*8 + j
    const short* qp = (const short*)qbf + (size_t)(head * QPH + qbase) * HS;
    bf16x8 qf[4][2];
    #pragma unroll
    for (int qt = 0; qt < 4; ++qt) {
        const short* qrow = qp + (qt * 16 + l15) * HS + quad * 8;
        qf[qt][0] = *(const bf16x8*)(qrow);
        qf[qt][1] = *(const bf16x8*)(qrow + 32);
    }

    const short* ep = (const short*)ebf + ((size_t)head * VOCAB + vslice * 512) * HS;
    const float* gp = g + head * VOCAB + vslice * 512;

    float num[4] = {0.f, 0.f, 0.f, 0.f};
    float den[4] = {0.f, 0.f, 0.f, 0.f};
    const f32x4 z = {0.f, 0.f, 0.f, 0.f};

    // prologue: load iteration 0's fragments
    const short* e0 = ep + (size_t)l15 * HS + quad * 8;
    const short* e1 = ep + (size_t)(16 + l15) * HS + quad * 8;
    bf16x8 a00 = *(const bf16x8*)(e0);
    bf16x8 a01 = *(const bf16x8*)(e0 + 32);
    bf16x8 a10 = *(const bf16x8*)(e1);
    bf16x8 a11 = *(const bf16x8*)(e1 + 32);
    f32x4 gv0 = *(const f32x4*)(gp + quad * 4);
    f32x4 gv1 = *(const f32x4*)(gp + 16 + quad * 4);

    #pragma clang loop unroll(disable)
    for (int it = 0; it < 16; ++it) {
        // issue next iteration's loads (wrap on last iter; values unused)
        int vb2 = ((it + 1) & 15) * 32;
        const short* n0 = ep + (size_t)(vb2 + l15) * HS + quad * 8;
        const short* n1 = ep + (size_t)(vb2 + 16 + l15) * HS + quad * 8;
        bf16x8 b00 = *(const bf16x8*)(n0);
        bf16x8 b01 = *(const bf16x8*)(n0 + 32);
        bf16x8 b10 = *(const bf16x8*)(n1);
        bf16x8 b11 = *(const bf16x8*)(n1 + 32);
        f32x4 ngv0 = *(const f32x4*)(gp + vb2 + quad * 4);
        f32x4 ngv1 = *(const f32x4*)(gp + vb2 + 16 + quad * 4);

        #pragma unroll
        for (int qt = 0; qt < 4; ++qt) {
            f32x4 acc0 = __builtin_amdgcn_mfma_f32_16x16x32_bf16(a00, qf[qt][0], z, 0, 0, 0);
            acc0       = __builtin_amdgcn_mfma_f32_16x16x32_bf16(a01, qf[qt][1], acc0, 0, 0, 0);
            f32x4 acc1 = __builtin_amdgcn_mfma_f32_16x16x32_bf16(a10, qf[qt][0], z, 0, 0, 0);
            acc1       = __builtin_amdgcn_mfma_f32_16x16x32_bf16(a11, qf[qt][1], acc1, 0, 0, 0);
            // D layout: col=l15=q, row=quad*4+r = v-within-16-tile
            #pragma unroll
            for (int r = 0; r < 4; ++r) {
                float p0 = fexp2(acc0[r]);
                float p1 = fexp2(acc1[r]);
                den[qt] += p0 + p1;
                num[qt] += p0 * gv0[r] + p1 * gv1[r];
            }
        }
        // rotate pipeline registers
        a00 = b00; a01 = b01; a10 = b10; a11 = b11;
        gv0 = ngv0; gv1 = ngv1;
    }

    // reduce across quads (same l15 = same q)
    #pragma unroll
    for (int qt = 0; qt < 4; ++qt) {
        num[qt] += __shfl_xor(num[qt], 16); num[qt] += __shfl_xor(num[qt], 32);
        den[qt] += __shfl_xor(den[qt], 16); den[qt] += __shfl_xor(den[qt], 32);
    }
    // slotted partials (no atomics, no memset): part[vslice][head][q]
    // quad i commits q-tile i: 16 lanes store one float2 each
    int qg = qbase + quad * 16 + l15;
    part[((size_t)vslice * NH + head) * QPH + qg] = make_float2(num[quad], den[quad]);
}

// ---------------- Kernel 3: out[q] = dec_b + sum_n (sum_s num)/(sum_s den) -----------
__global__ void fin(const float2* __restrict__ part, const float* __restrict__ dec_b,
                    float* __restrict__ out) {
    int q = blockIdx.x * 256 + threadIdx.x;   // 0..2047
    float s = dec_b[0];
    #pragma unroll
    for (int n = 0; n < NH; ++n) {
        float nv = 0.f, dv = 0.f;
        #pragma unroll 4
        for (int sl = 0; sl < NSLICE; ++sl) {
            float2 nd = part[((size_t)sl * NH + n) * QPH + q];
            nv += nd.x; dv += nd.y;
        }
        s += nv / dv;
    }
    out[q] = s;
}

extern "C" void kernel_launch(void* const* d_in, const int* in_sizes, int n_in,
                              void* d_out, int out_size, void* d_ws, size_t ws_size,
                              hipStream_t stream) {
    const float* x     = (const float*)d_in[0];
    const float* emb   = (const float*)d_in[1];
    const float* enc_w = (const float*)d_in[2];
    const float* enc_b = (const float*)d_in[3];
    const float* ln_w  = (const float*)d_in[4];
    const float* ln_b  = (const float*)d_in[5];
    const float* dec_w = (const float*)d_in[6];
    const float* dec_b = (const float*)d_in[7];
    float* out = (float*)d_out;

    char* ws = (char*)d_ws;
    unsigned short* qbf  = (unsigned short*)(ws);                        // 2 MB
    unsigned short* ebf  = (unsigned short*)(ws + 2097152);              // 16 MB
    float*          g    = (float*)(ws + 2097152 + 16777216);            // 512 KB
    float2*         part = (float2*)(ws + 2097152 + 16777216 + 524288);  // 4 MB (32*8*2048 float2)

    hipLaunchKernelGGL(prep, dim3(12288), dim3(256), 0, stream,
                       x, emb, enc_w, enc_b, ln_w, ln_b, dec_w, qbf, ebf, g);
    hipLaunchKernelGGL(attn, dim3(2048), dim3(256), 0, stream, qbf, ebf, g, part);
    hipLaunchKernelGGL(fin,  dim3(8),    dim3(256), 0, stream, part, dec_b, out);
}

// Round 9
// 166.798 us; speedup vs baseline: 1.1295x; 1.1295x over previous
//
#include <hip/hip_runtime.h>
#include <hip/hip_bf16.h>
#include <math.h>

#define NH 8
#define HS 64
#define VOCAB 16384
#define QPH 2048                         // queries per head = b(4) * t(512)
#define NSLICE 32                        // vocab slices (512 rows each)
// fold 1/sqrt(512) * log2(e) into Q so the epilogue is p = exp2(score)
#define QSCALE (0.04419417382415922f * 1.4426950408889634f)

typedef __attribute__((ext_vector_type(8))) short bf16x8;
typedef __attribute__((ext_vector_type(4))) float f32x4;

static __device__ __forceinline__ unsigned short f2bf(float f) {
    __hip_bfloat16 h = __float2bfloat16(f);
    unsigned short u;
    __builtin_memcpy(&u, &h, 2);
    return u;
}

static __device__ __forceinline__ float fexp2(float x) {
#if __has_builtin(__builtin_amdgcn_exp2f)
    return __builtin_amdgcn_exp2f(x);     // v_exp_f32 directly
#else
    return __expf(x * 0.6931471805599453f);
#endif
}

// ---------------- Kernel 1: fused prep -----------------------------------------------
// blocks [0,8192):   E -> bf16 cast + g[n][v] = E[n][v,:] . dec_w[n*64:]
// blocks [8192,12288): Q = LayerNorm(enc(x) + PE) * QSCALE -> bf16, wave per row
__global__ void prep(const float* __restrict__ x, const float* __restrict__ emb,
                     const float* __restrict__ enc_w, const float* __restrict__ enc_b,
                     const float* __restrict__ ln_w, const float* __restrict__ ln_b,
                     const float* __restrict__ dec_w,
                     unsigned short* __restrict__ qbf, unsigned short* __restrict__ ebf,
                     float* __restrict__ g) {
    if (blockIdx.x < 8192) {
        int i4  = blockIdx.x * 256 + threadIdx.x;   // float4 index, total 2097152
        int row = i4 >> 4;                          // (n, v) row
        int c   = i4 & 15;
        int n   = row >> 14;
        f32x4 v = ((const f32x4*)emb)[i4];
        ushort4 u = make_ushort4(f2bf(v.x), f2bf(v.y), f2bf(v.z), f2bf(v.w));
        ((ushort4*)ebf)[i4] = u;
        const float* dw = dec_w + n * 64 + c * 4;
        float p = v.x * dw[0] + v.y * dw[1] + v.z * dw[2] + v.w * dw[3];
        p += __shfl_xor(p, 1); p += __shfl_xor(p, 2);
        p += __shfl_xor(p, 4); p += __shfl_xor(p, 8);
        if (c == 0) g[row] = p;
    } else {
        int row  = (blockIdx.x - 8192) * 4 + (threadIdx.x >> 6);  // n*2048 + q
        int h    = threadIdx.x & 63;
        int n = row >> 11;
        int q = row & 2047;
        int t = q & 511;
        float xv = x[q];
        int d = n * 64 + h;
        float h2  = (float)(h & ~1);
        float div = __expf(h2 * (-9.210340371976184f / 64.0f));
        float ang = (float)t * div;
        float pe  = (h & 1) ? __cosf(ang) : __sinf(ang);
        float v = xv * enc_w[d] + enc_b[d] + pe;
        float s = v;
        #pragma unroll
        for (int off = 1; off < 64; off <<= 1) s += __shfl_xor(s, off);
        float mu = s * (1.0f / 64.0f);
        float dd = v - mu;
        float s2 = dd * dd;
        #pragma unroll
        for (int off = 1; off < 64; off <<= 1) s2 += __shfl_xor(s2, off);
        float var = s2 * (1.0f / 64.0f);
        float y = dd * rsqrtf(var + 1e-5f) * ln_w[h] + ln_b[h];
        qbf[row * 64 + h] = f2bf(y * QSCALE);
    }
}

// ---------------- Kernel 2: attn -----------------------------------------------------
// grid 1024 = qchunk(4)*256 + vslice(32)*8 + head(8); block 256 (4 waves).
// blockIdx % 8 == head: each XCD's share touches ONE head's E (2MB < 4MB L2).
// Wave w: 128 q (8 MFMA q-tiles, Q persistent 64 VGPR) x 512-row vocab slice,
// trip-16 K-loop (unroll disabled). Per iter: 6 loads feed 32 MFMA + ~770 VALU
// cyc — double R3's compute-per-stall (kernel is VMEM-latency bound; occupancy
// is pinned ~40% regardless of grid, so density is the only lever — R8).
// CODEGEN NOTES (hard-won):
//  - __launch_bounds__(256,3): ~140 VGPR needed; (256,4) caps at 128 -> spill
//    (R4-class disaster: WRITE explodes). 3 waves/SIMD is the plan.
//  - K-loop must NOT fully unroll (R5: in-loop spill, FETCH 384MB). Guarded.
//  - q/wave is the efficiency currency: 32q=143us, 64q=82us (R6/R3). Now 128q.
//  - manual prefetch is NOT load-bearing (R7: compiler sinks it). Dropped.
__global__ void __launch_bounds__(256, 3)
attn(const unsigned short* __restrict__ qbf, const unsigned short* __restrict__ ebf,
     const float* __restrict__ g, float2* __restrict__ part) {
    int tid  = threadIdx.x;
    int w    = tid >> 6;
    int lane = tid & 63;
    int quad = lane >> 4;
    int l15  = lane & 15;
    int head   = blockIdx.x & 7;
    int vslice = (blockIdx.x >> 3) & 31;   // 32 slices x 512 rows
    int qchunk = blockIdx.x >> 8;          // 4 chunks x 512 q
    int qbase  = (qchunk * 4 + w) * 128;   // 128 q per wave

    // persistent Q B-frags: B[k=hs][n=q], lane: n=l15, k = kf*32 + quad*8 + j
    const short* qp = (const short*)qbf + (size_t)(head * QPH + qbase) * HS;
    bf16x8 qf[8][2];
    #pragma unroll
    for (int qt = 0; qt < 8; ++qt) {
        const short* qrow = qp + (qt * 16 + l15) * HS + quad * 8;
        qf[qt][0] = *(const bf16x8*)(qrow);
        qf[qt][1] = *(const bf16x8*)(qrow + 32);
    }

    const short* ep = (const short*)ebf + ((size_t)head * VOCAB + vslice * 512) * HS;
    const float* gp = g + head * VOCAB + vslice * 512;

    float num[8] = {0.f, 0.f, 0.f, 0.f, 0.f, 0.f, 0.f, 0.f};
    float den[8] = {0.f, 0.f, 0.f, 0.f, 0.f, 0.f, 0.f, 0.f};
    const f32x4 z = {0.f, 0.f, 0.f, 0.f};

    #pragma clang loop unroll(disable)
    for (int it = 0; it < 16; ++it) {
        int vb = it * 32;
        // A-frags direct from global (L2): A[m=v][k], lane: m=l15(+16), k=kf*32+quad*8+j
        const short* e0 = ep + (size_t)(vb + l15) * HS + quad * 8;
        const short* e1 = ep + (size_t)(vb + 16 + l15) * HS + quad * 8;
        bf16x8 a00 = *(const bf16x8*)(e0);
        bf16x8 a01 = *(const bf16x8*)(e0 + 32);
        bf16x8 a10 = *(const bf16x8*)(e1);
        bf16x8 a11 = *(const bf16x8*)(e1 + 32);
        f32x4 gv0 = *(const f32x4*)(gp + vb + quad * 4);
        f32x4 gv1 = *(const f32x4*)(gp + vb + 16 + quad * 4);
        #pragma unroll
        for (int qt = 0; qt < 8; ++qt) {
            f32x4 acc0 = __builtin_amdgcn_mfma_f32_16x16x32_bf16(a00, qf[qt][0], z, 0, 0, 0);
            acc0       = __builtin_amdgcn_mfma_f32_16x16x32_bf16(a01, qf[qt][1], acc0, 0, 0, 0);
            f32x4 acc1 = __builtin_amdgcn_mfma_f32_16x16x32_bf16(a10, qf[qt][0], z, 0, 0, 0);
            acc1       = __builtin_amdgcn_mfma_f32_16x16x32_bf16(a11, qf[qt][1], acc1, 0, 0, 0);
            // D layout: col=l15=q, row=quad*4+r = v-within-16-tile
            #pragma unroll
            for (int r = 0; r < 4; ++r) {
                float p0 = fexp2(acc0[r]);
                float p1 = fexp2(acc1[r]);
                den[qt] += p0 + p1;
                num[qt] += p0 * gv0[r] + p1 * gv1[r];
            }
        }
    }

    // reduce across quads (same l15 = same q)
    #pragma unroll
    for (int qt = 0; qt < 8; ++qt) {
        num[qt] += __shfl_xor(num[qt], 16); num[qt] += __shfl_xor(num[qt], 32);
        den[qt] += __shfl_xor(den[qt], 16); den[qt] += __shfl_xor(den[qt], 32);
    }
    // slotted partials (no atomics): part[vslice][head][q]; quad commits 2 tiles
    #pragma unroll
    for (int j = 0; j < 2; ++j) {
        int qt = quad * 2 + j;
        int qg = qbase + qt * 16 + l15;
        part[((size_t)vslice * NH + head) * QPH + qg] = make_float2(num[qt], den[qt]);
    }
}

// ---------------- Kernel 3: out[q] = dec_b + sum_n (sum_s num)/(sum_s den) -----------
__global__ void fin(const float2* __restrict__ part, const float* __restrict__ dec_b,
                    float* __restrict__ out) {
    int q = blockIdx.x * 256 + threadIdx.x;   // 0..2047
    float s = dec_b[0];
    #pragma unroll
    for (int n = 0; n < NH; ++n) {
        float nv = 0.f, dv = 0.f;
        #pragma unroll 4
        for (int sl = 0; sl < NSLICE; ++sl) {
            float2 nd = part[((size_t)sl * NH + n) * QPH + q];
            nv += nd.x; dv += nd.y;
        }
        s += nv / dv;
    }
    out[q] = s;
}

extern "C" void kernel_launch(void* const* d_in, const int* in_sizes, int n_in,
                              void* d_out, int out_size, void* d_ws, size_t ws_size,
                              hipStream_t stream) {
    const float* x     = (const float*)d_in[0];
    const float* emb   = (const float*)d_in[1];
    const float* enc_w = (const float*)d_in[2];
    const float* enc_b = (const float*)d_in[3];
    const float* ln_w  = (const float*)d_in[4];
    const float* ln_b  = (const float*)d_in[5];
    const float* dec_w = (const float*)d_in[6];
    const float* dec_b = (const float*)d_in[7];
    float* out = (float*)d_out;

    char* ws = (char*)d_ws;
    unsigned short* qbf  = (unsigned short*)(ws);                        // 2 MB
    unsigned short* ebf  = (unsigned short*)(ws + 2097152);              // 16 MB
    float*          g    = (float*)(ws + 2097152 + 16777216);            // 512 KB
    float2*         part = (float2*)(ws + 2097152 + 16777216 + 524288);  // 4 MB (32*8*2048 float2)

    hipLaunchKernelGGL(prep, dim3(12288), dim3(256), 0, stream,
                       x, emb, enc_w, enc_b, ln_w, ln_b, dec_w, qbf, ebf, g);
    hipLaunchKernelGGL(attn, dim3(1024), dim3(256), 0, stream, qbf, ebf, g, part);
    hipLaunchKernelGGL(fin,  dim3(8),    dim3(256), 0, stream, part, dec_b, out);
}